// Round 7
// baseline (360.407 us; speedup 1.0000x reference)
//
#include <hip/hip_runtime.h>

// Fused binary-sign depthwise conv:
//   out = dwconv(sign(x), w) + dwconv(x, sign(w)), 3x3, stride 1, pad 1
// x: [N=32, C=128, H=112, W=112] fp32, w: [128,1,3,3] fp32, out same shape.
//
// R6 post-mortem: register-ring kernel beat the 127us poison-fills (<=125us,
// down from 166us). Residual ~2x vs the 64us memory floor = load-use stall:
// each STEP consumed its bottom-row load immediately. This round: explicit
// software pipeline — 4-deep V-ring, prefetch row i+2 while computing row i,
// sign of a row computed one full step after its load is issued.

#define CH    128
#define HH    112
#define WW    112
#define NW4   28            // 112/4 float4 columns
#define PLANE (HH * WW)
#define RPT   7             // output rows per thread
#define NRG   (HH / RPT)    // 16 row-groups
#define NTHR  (NW4 * NRG)   // 448 threads = 7 waves

__device__ __forceinline__ float sgn(float v) {
    // +-1 with v's sign, 0 for +-0
    float one = __uint_as_float(0x3f800000u | (__float_as_uint(v) & 0x80000000u));
    return (v == 0.0f) ? 0.0f : one;
}

// Load one input row (6 vals: col-1 .. col+4), zero outside the image.
#define LOADROW(r, V)                                                 \
  {                                                                   \
    const int rr_ = (r);                                              \
    if (rr_ >= 0 && rr_ < HH) {                                       \
      const float* row_ = xc + rr_ * WW + col;                        \
      const float4 m_ = *reinterpret_cast<const float4*>(row_);       \
      V[1] = m_.x; V[2] = m_.y; V[3] = m_.z; V[4] = m_.w;             \
      V[0] = has_l ? row_[-1] : 0.0f;                                 \
      V[5] = has_r ? row_[4]  : 0.0f;                                 \
    } else {                                                          \
      V[0] = V[1] = V[2] = V[3] = V[4] = V[5] = 0.0f;                 \
    }                                                                 \
  }

#define SIGNROW(V, S)                                                 \
  { S[0]=sgn(V[0]); S[1]=sgn(V[1]); S[2]=sgn(V[2]);                   \
    S[3]=sgn(V[3]); S[4]=sgn(V[4]); S[5]=sgn(V[5]); }

// Accumulate one kernel row dr (weights W/Q uniform -> SGPR) into a0..a3.
#define ACCR(V, S, dr)                                                        \
    a0 = fmaf(S[0], W[3*(dr)+0], fmaf(V[0], Q[3*(dr)+0], a0));                \
    a0 = fmaf(S[1], W[3*(dr)+1], fmaf(V[1], Q[3*(dr)+1], a0));                \
    a0 = fmaf(S[2], W[3*(dr)+2], fmaf(V[2], Q[3*(dr)+2], a0));                \
    a1 = fmaf(S[1], W[3*(dr)+0], fmaf(V[1], Q[3*(dr)+0], a1));                \
    a1 = fmaf(S[2], W[3*(dr)+1], fmaf(V[2], Q[3*(dr)+1], a1));                \
    a1 = fmaf(S[3], W[3*(dr)+2], fmaf(V[3], Q[3*(dr)+2], a1));                \
    a2 = fmaf(S[2], W[3*(dr)+0], fmaf(V[2], Q[3*(dr)+0], a2));                \
    a2 = fmaf(S[3], W[3*(dr)+1], fmaf(V[3], Q[3*(dr)+1], a2));                \
    a2 = fmaf(S[4], W[3*(dr)+2], fmaf(V[4], Q[3*(dr)+2], a2));                \
    a3 = fmaf(S[3], W[3*(dr)+0], fmaf(V[3], Q[3*(dr)+0], a3));                \
    a3 = fmaf(S[4], W[3*(dr)+1], fmaf(V[4], Q[3*(dr)+1], a3));                \
    a3 = fmaf(S[5], W[3*(dr)+2], fmaf(V[5], Q[3*(dr)+2], a3));

// Pipelined step: prefetch row (i+2) into the slot VP that died last step,
// THEN compute output row i from rows loaded >=1 step ago. SB_ = sign of the
// bottom row VB_ (loaded last step), computed here, reused for 2 more steps.
#define STEPP(i, VT, ST, VM, SM, VB_, SB_, VP)                        \
  {                                                                   \
    LOADROW(rbase + (i) + 2, VP);  /* independent prefetch */         \
    SIGNROW(VB_, SB_);             /* load landed a step ago */       \
    float a0 = 0.f, a1 = 0.f, a2 = 0.f, a3 = 0.f;                     \
    ACCR(VT, ST, 0);                                                  \
    ACCR(VM, SM, 1);                                                  \
    ACCR(VB_, SB_, 2);                                                \
    float4 o_; o_.x = a0; o_.y = a1; o_.z = a2; o_.w = a3;            \
    *reinterpret_cast<float4*>(oc + (rbase + (i)) * WW + col) = o_;   \
  }

// Last step: no prefetch.
#define STEPL(i, VT, ST, VM, SM, VB_, SB_)                            \
  {                                                                   \
    SIGNROW(VB_, SB_);                                                \
    float a0 = 0.f, a1 = 0.f, a2 = 0.f, a3 = 0.f;                     \
    ACCR(VT, ST, 0);                                                  \
    ACCR(VM, SM, 1);                                                  \
    ACCR(VB_, SB_, 2);                                                \
    float4 o_; o_.x = a0; o_.y = a1; o_.z = a2; o_.w = a3;            \
    *reinterpret_cast<float4*>(oc + (rbase + (i)) * WW + col) = o_;   \
  }

__global__ __launch_bounds__(NTHR) void bisign_dwconv_kernel(
    const float* __restrict__ x,
    const float* __restrict__ wt,
    float* __restrict__ out)
{
    const int plane = blockIdx.x;              // n*CH + c
    const int c = plane & (CH - 1);

    const float* __restrict__ xc = x   + (size_t)plane * PLANE;
    float* __restrict__       oc = out + (size_t)plane * PLANE;

    // 9 taps, block-uniform channel -> scalar weights (SGPR)
    float W[9], Q[9];
#pragma unroll
    for (int k = 0; k < 9; ++k) {
        const float wv = wt[c * 9 + k];
        W[k] = wv;
        Q[k] = sgn(wv);
    }

    const int tid   = threadIdx.x;
    const int col4  = tid % NW4;               // 0..27
    const int rg    = tid / NW4;               // 0..15
    const int col   = col4 * 4;
    const int rbase = rg * RPT;

    const bool has_l = (col4 > 0);
    const bool has_r = (col4 < NW4 - 1);

    // 4-deep value ring + 3-deep sign ring, all statically indexed.
    float VA[6], VB[6], VC[6], VD[6];
    float SA[6], SB[6], SC[6];

    // Prologue: rows r-1, r0, r1 in flight; signs of r-1, r0.
    LOADROW(rbase - 1, VA);
    LOADROW(rbase,     VB);
    LOADROW(rbase + 1, VC);
    SIGNROW(VA, SA);
    SIGNROW(VB, SB);

    //      i   top     mid     bot(new sign)   prefetch slot (row i+2)
    STEPP(0,  VA, SA,  VB, SB,  VC, SC,        VD);
    STEPP(1,  VB, SB,  VC, SC,  VD, SA,        VA);
    STEPP(2,  VC, SC,  VD, SA,  VA, SB,        VB);
    STEPP(3,  VD, SA,  VA, SB,  VB, SC,        VC);
    STEPP(4,  VA, SB,  VB, SC,  VC, SA,        VD);
    STEPP(5,  VB, SC,  VC, SA,  VD, SB,        VA);
    STEPL(6,  VC, SA,  VD, SB,  VA, SC);
}

extern "C" void kernel_launch(void* const* d_in, const int* in_sizes, int n_in,
                              void* d_out, int out_size, void* d_ws, size_t ws_size,
                              hipStream_t stream) {
    const float* x  = (const float*)d_in[0];
    const float* wt = (const float*)d_in[1];
    float* out = (float*)d_out;

    const int N = in_sizes[0] / (CH * PLANE);   // 32
    const int nblocks = N * CH;                 // one block per (n, c) plane

    bisign_dwconv_kernel<<<nblocks, NTHR, 0, stream>>>(x, wt, out);
}

// Round 8
// 348.457 us; speedup vs baseline: 1.0343x; 1.0343x over previous
//
#include <hip/hip_runtime.h>

// Fused binary-sign depthwise conv:
//   out = dwconv(sign(x), w) + dwconv(x, sign(w)), 3x3, stride 1, pad 1
// x: [N=32, C=128, H=112, W=112] fp32, w: [128,1,3,3] fp32, out same shape.
//
// R7 post-mortem: explicit SW pipeline was NEUTRAL (kernel ~124us both R6/R7;
// compiler had already pipelined). Residual vs 48us HBM floor blamed on
// (1) 34 VMEM instrs/thread (18 scalar edge loads) and (2) divergent
// bounds-check branches fragmenting the schedule. This round:
//  - 32-lane row segments (28 active): halo via __shfl_up/__shfl_down of
//    neighbor-lane float4 components -> 16 VMEM instrs/thread, all dwordx4.
//  - branchless OOB: clamp row addr + cndmask-zero (only rows rbase-1 and
//    rbase+7 can be OOB) -> single straight-line basic block.

#define CH    128
#define HH    112
#define WW    112
#define NW4   28            // 112/4 float4 columns (active lanes per row)
#define LPR   32            // lanes per row segment (28 active + 4 pad)
#define PLANE (HH * WW)
#define RPT   7             // output rows per thread
#define NRG   16            // row groups
#define NTHR  (LPR * NRG)   // 512 threads = 8 waves

__device__ __forceinline__ float sgn(float v) {
    // +-1 with v's sign, 0 for +-0
    float one = __uint_as_float(0x3f800000u | (__float_as_uint(v) & 0x80000000u));
    return (v == 0.0f) ? 0.0f : one;
}

// Always-in-bounds row load: one coalesced dwordx4, no branch.
#define LOAD_SAFE(r, M)                                               \
    M = *reinterpret_cast<const float4*>(xc + (r) * WW + col);

// Possibly-OOB row (only rbase-1 / rbase+7): clamp addr, cndmask-zero payload.
#define LOAD_EDGE(r, M)                                               \
  {                                                                   \
    const int rr_  = ((r) < 0) ? 0 : (((r) > HH - 1) ? HH - 1 : (r)); \
    const bool ob_ = ((r) < 0) | ((r) > HH - 1);                      \
    M = *reinterpret_cast<const float4*>(xc + rr_ * WW + col);        \
    M.x = ob_ ? 0.f : M.x;  M.y = ob_ ? 0.f : M.y;                    \
    M.z = ob_ ? 0.f : M.z;  M.w = ob_ ? 0.f : M.w;                    \
  }

// Expand raw float4 into 6-wide window + signs. Halo from neighbor lanes.
// Lane col4==0 is the image left edge (v0=0); col4==27 the right (v5=0);
// row-segment boundaries inside a wave coincide with those masks.
#define EXPAND(M, V, S)                                               \
  {                                                                   \
    V[1] = M.x; V[2] = M.y; V[3] = M.z; V[4] = M.w;                   \
    const float up_ = __shfl_up(M.w, 1, 64);                          \
    const float dn_ = __shfl_down(M.x, 1, 64);                        \
    V[0] = (col4 == 0)       ? 0.f : up_;                             \
    V[5] = (col4 == NW4 - 1) ? 0.f : dn_;                             \
    S[0] = sgn(V[0]); S[1] = sgn(V[1]); S[2] = sgn(V[2]);             \
    S[3] = sgn(V[3]); S[4] = sgn(V[4]); S[5] = sgn(V[5]);             \
  }

// Accumulate one kernel row dr (weights W/Q block-uniform -> scalar).
#define ACCR(V, S, dr)                                                        \
    a0 = fmaf(S[0], W[3*(dr)+0], fmaf(V[0], Q[3*(dr)+0], a0));                \
    a0 = fmaf(S[1], W[3*(dr)+1], fmaf(V[1], Q[3*(dr)+1], a0));                \
    a0 = fmaf(S[2], W[3*(dr)+2], fmaf(V[2], Q[3*(dr)+2], a0));                \
    a1 = fmaf(S[1], W[3*(dr)+0], fmaf(V[1], Q[3*(dr)+0], a1));                \
    a1 = fmaf(S[2], W[3*(dr)+1], fmaf(V[2], Q[3*(dr)+1], a1));                \
    a1 = fmaf(S[3], W[3*(dr)+2], fmaf(V[3], Q[3*(dr)+2], a1));                \
    a2 = fmaf(S[2], W[3*(dr)+0], fmaf(V[2], Q[3*(dr)+0], a2));                \
    a2 = fmaf(S[3], W[3*(dr)+1], fmaf(V[3], Q[3*(dr)+1], a2));                \
    a2 = fmaf(S[4], W[3*(dr)+2], fmaf(V[4], Q[3*(dr)+2], a2));                \
    a3 = fmaf(S[3], W[3*(dr)+0], fmaf(V[3], Q[3*(dr)+0], a3));                \
    a3 = fmaf(S[4], W[3*(dr)+1], fmaf(V[4], Q[3*(dr)+1], a3));                \
    a3 = fmaf(S[5], W[3*(dr)+2], fmaf(V[5], Q[3*(dr)+2], a3));

// One step: PRE = prefetch row i+2 into dead raw slot; EXP = expand the row
// loaded last step (row i+1); then accumulate rows i-1,i,i+1 and store row i.
#define STEP(i, PRE, EXP, EVt, ESt, EVm, ESm, EVb, ESb)               \
  {                                                                   \
    PRE;                                                              \
    EXP;                                                              \
    float a0 = 0.f, a1 = 0.f, a2 = 0.f, a3 = 0.f;                     \
    ACCR(EVt, ESt, 0);                                                \
    ACCR(EVm, ESm, 1);                                                \
    ACCR(EVb, ESb, 2);                                                \
    if (col4 < NW4) {                                                 \
      float4 o_; o_.x = a0; o_.y = a1; o_.z = a2; o_.w = a3;          \
      *reinterpret_cast<float4*>(oc + (rbase + (i)) * WW + col) = o_; \
    }                                                                 \
  }

__global__ __launch_bounds__(NTHR) void bisign_dwconv_kernel(
    const float* __restrict__ x,
    const float* __restrict__ wt,
    float* __restrict__ out)
{
    const int plane = blockIdx.x;              // n*CH + c
    const int c = plane & (CH - 1);

    const float* __restrict__ xc = x   + (size_t)plane * PLANE;
    float* __restrict__       oc = out + (size_t)plane * PLANE;

    // 9 taps, block-uniform channel -> scalar weights
    float W[9], Q[9];
#pragma unroll
    for (int k = 0; k < 9; ++k) {
        const float wv = wt[c * 9 + k];
        W[k] = wv;
        Q[k] = sgn(wv);
    }

    const int tid   = threadIdx.x;
    const int col4  = tid & (LPR - 1);         // 0..31 (28 active)
    const int rseg  = tid >> 5;                // 0..15
    const int col4c = (col4 < NW4 - 1) ? col4 : NW4 - 1;   // clamp pad lanes
    const int col   = col4c * 4;
    const int rbase = rseg * RPT;

    // Raw float4 ring (4-deep) + expanded window ring (3-deep), all static.
    float4 MA, MB, MC, MD;
    float EAv[6], EAs[6], EBv[6], EBs[6], ECv[6], ECs[6];

    // Prologue: rows rbase-1 (edge), rbase, rbase+1 in flight; expand first 2.
    LOAD_EDGE(rbase - 1, MA);
    LOAD_SAFE(rbase,     MB);
    LOAD_SAFE(rbase + 1, MC);
    EXPAND(MA, EAv, EAs);
    EXPAND(MB, EBv, EBs);

    STEP(0, LOAD_SAFE(rbase + 2, MD), EXPAND(MC, ECv, ECs), EAv, EAs, EBv, EBs, ECv, ECs);
    STEP(1, LOAD_SAFE(rbase + 3, MA), EXPAND(MD, EAv, EAs), EBv, EBs, ECv, ECs, EAv, EAs);
    STEP(2, LOAD_SAFE(rbase + 4, MB), EXPAND(MA, EBv, EBs), ECv, ECs, EAv, EAs, EBv, EBs);
    STEP(3, LOAD_SAFE(rbase + 5, MC), EXPAND(MB, ECv, ECs), EAv, EAs, EBv, EBs, ECv, ECs);
    STEP(4, LOAD_SAFE(rbase + 6, MD), EXPAND(MC, EAv, EAs), EBv, EBs, ECv, ECs, EAv, EAs);
    STEP(5, LOAD_EDGE(rbase + 7, MA), EXPAND(MD, EBv, EBs), ECv, ECs, EAv, EAs, EBv, EBs);
    STEP(6, ((void)0),                EXPAND(MA, ECv, ECs), EAv, EAs, EBv, EBs, ECv, ECs);
}

extern "C" void kernel_launch(void* const* d_in, const int* in_sizes, int n_in,
                              void* d_out, int out_size, void* d_ws, size_t ws_size,
                              hipStream_t stream) {
    const float* x  = (const float*)d_in[0];
    const float* wt = (const float*)d_in[1];
    float* out = (float*)d_out;

    const int N = in_sizes[0] / (CH * PLANE);   // 32
    const int nblocks = N * CH;                 // one block per (n, c) plane

    bisign_dwconv_kernel<<<nblocks, NTHR, 0, stream>>>(x, wt, out);
}